// Round 4
// baseline (291.131 us; speedup 1.0000x reference)
//
#include <hip/hip_runtime.h>

typedef short bf16x8 __attribute__((ext_vector_type(8)));
typedef float f32x4 __attribute__((ext_vector_type(4)));

#define MFMA16(a,b,c) __builtin_amdgcn_mfma_f32_16x16x32_bf16((a),(b),(c),0,0,0)

static __device__ __forceinline__ unsigned short f2bf(float f){
  unsigned u; __builtin_memcpy(&u, &f, 4);
  u += 0x7fffu + ((u >> 16) & 1u);
  return (unsigned short)(u >> 16);
}

// ---------------------------------------------------------------------------
// Stage f32 tensor -> bf16.
// ---------------------------------------------------------------------------
__global__ __launch_bounds__(256) void cvt_bf16(
    const float* __restrict__ in, unsigned short* __restrict__ out, int n) {
  int i = blockIdx.x * 256 + threadIdx.x;
  if (i < n) out[i] = f2bf(in[i]);
}

// ---------------------------------------------------------------------------
// T0: x [n][512 c][1024 p] f32 -> xT [n][1024 p][512 c] bf16
// ---------------------------------------------------------------------------
__global__ __launch_bounds__(256) void transpose_cvt(
    const float* __restrict__ in, unsigned short* __restrict__ out)
{
  __shared__ unsigned short tile[32][33];
  const long base = (long)blockIdx.z * 512 * 1024;
  const int t = threadIdx.x, tx = t & 31, ty = t >> 5;
  const int c0 = blockIdx.x * 32, r0 = blockIdx.y * 32;
  const float* ib = in + base;
#pragma unroll
  for (int i = 0; i < 4; ++i)
    tile[ty + i * 8][tx] = f2bf(ib[(long)(r0 + ty + i * 8) * 1024 + c0 + tx]);
  __syncthreads();
  unsigned short* ob = out + base;
#pragma unroll
  for (int i = 0; i < 4; ++i)
    ob[(long)(c0 + ty + i * 8) * 512 + r0 + tx] = tile[tx][ty + i * 8];
}

// ---------------------------------------------------------------------------
// K1: QKV GEMM.  A = xT [n][1024 p][512 c] bf16, B = wq [1536 o][512 c] bf16,
// bias f32. Epilogue routes by o:
//   o in [0,512)    -> q_pd [n][h][p][64]   (qkv + 0)
//   o in [512,1024) -> k_pd [n][h][p][64]   (qkv + 8388608)
//   o in [1024,1536)-> v_cp [n][o-1024][p]  (qkv + 16777216)
// ---------------------------------------------------------------------------
__global__ __launch_bounds__(256) void gemm_qkv(
    const unsigned short* __restrict__ A, const unsigned short* __restrict__ B,
    unsigned short* __restrict__ qkvout, const float* __restrict__ bias)
{
  const int M = 1024, K = 512;
  __shared__ unsigned short As[128 * 72];
  __shared__ unsigned short Bs[128 * 72];
  const int t = threadIdx.x, lane = t & 63, wv = t >> 6;
  const int quad = lane >> 4, ln = lane & 15;
  const int m0 = blockIdx.y * 128, n0 = blockIdx.x * 128;
  const long zb = blockIdx.z;
  A += zb * (long)M * K;

  f32x4 zero = {0.f, 0.f, 0.f, 0.f};
  f32x4 acc[4][4];
#pragma unroll
  for (int i = 0; i < 4; ++i)
#pragma unroll
    for (int j = 0; j < 4; ++j) acc[i][j] = zero;

  const int wm = (wv & 1) * 64, wn = (wv >> 1) * 64;

  for (int kt = 0; kt < K; kt += 64) {
#pragma unroll
    for (int i = 0; i < 4; ++i) {
      int chunk = t + 256 * i;
      int row = chunk >> 3, col = (chunk & 7) * 8;
      *(uint4*)&As[row * 72 + col] = *(const uint4*)&A[(long)(m0 + row) * K + kt + col];
      *(uint4*)&Bs[row * 72 + col] = *(const uint4*)&B[(long)(n0 + row) * K + kt + col];
    }
    __syncthreads();
#pragma unroll
    for (int kk = 0; kk < 64; kk += 32) {
      bf16x8 a[4], b[4];
#pragma unroll
      for (int i = 0; i < 4; ++i)
        a[i] = *(const bf16x8*)&As[(wm + i * 16 + ln) * 72 + kk + quad * 8];
#pragma unroll
      for (int j = 0; j < 4; ++j)
        b[j] = *(const bf16x8*)&Bs[(wn + j * 16 + ln) * 72 + kk + quad * 8];
#pragma unroll
      for (int i = 0; i < 4; ++i)
#pragma unroll
        for (int j = 0; j < 4; ++j)
          acc[i][j] = MFMA16(a[i], b[j], acc[i][j]);
    }
    __syncthreads();
  }

#pragma unroll
  for (int j = 0; j < 4; ++j) {
    int o = n0 + wn + j * 16 + ln;
    float bb = bias[o];
    int part = o >> 9;          // 0=q, 1=k, 2=v
    int h = (o >> 6) & 7, d = o & 63;
#pragma unroll
    for (int i = 0; i < 4; ++i) {
      int p = m0 + wm + i * 16 + quad * 4;
      f32x4 v = acc[i][j];
      if (part < 2) {
        unsigned short* dst = qkvout + (long)part * 8388608
            + ((long)(zb * 8 + h) * 1024 + p) * 64 + d;
#pragma unroll
        for (int r = 0; r < 4; ++r) dst[r * 64] = f2bf(v[r] + bb);
      } else {
        long cidx = ((long)zb * 512 + (o - 1024)) * 1024 + p;
        ushort4 st;
        st.x = f2bf(v[0] + bb); st.y = f2bf(v[1] + bb);
        st.z = f2bf(v[2] + bb); st.w = f2bf(v[3] + bb);
        *(ushort4*)&qkvout[16777216 + cidx] = st;
      }
    }
  }
}

// ---------------------------------------------------------------------------
// K3: OUT GEMM + bias + dropout-scale + residual; f32 output.
// A = y_pc [n][1024 p][512 c'] bf16, B = wo [512 o][512 c'] bf16,
// resid = x f32 [n][512][1024], out f32 [n][512][1024].
// ---------------------------------------------------------------------------
__global__ __launch_bounds__(256) void gemm_out(
    const unsigned short* __restrict__ A, const unsigned short* __restrict__ B,
    float* __restrict__ C, const float* __restrict__ bias,
    const float* __restrict__ xin, const int* __restrict__ de_ptr)
{
  const int M = 1024, K = 512;
  __shared__ unsigned short As[128 * 72];
  __shared__ unsigned short Bs[128 * 72];
  const int t = threadIdx.x, lane = t & 63, wv = t >> 6;
  const int quad = lane >> 4, ln = lane & 15;
  const int m0 = blockIdx.y * 128, n0 = blockIdx.x * 128;
  const long zb = blockIdx.z;
  A += zb * (long)M * K;
  C += zb * 512l * M;
  xin += zb * 512l * M;

  f32x4 zero = {0.f, 0.f, 0.f, 0.f};
  f32x4 acc[4][4];
#pragma unroll
  for (int i = 0; i < 4; ++i)
#pragma unroll
    for (int j = 0; j < 4; ++j) acc[i][j] = zero;

  const int wm = (wv & 1) * 64, wn = (wv >> 1) * 64;

  for (int kt = 0; kt < K; kt += 64) {
#pragma unroll
    for (int i = 0; i < 4; ++i) {
      int chunk = t + 256 * i;
      int row = chunk >> 3, col = (chunk & 7) * 8;
      *(uint4*)&As[row * 72 + col] = *(const uint4*)&A[(long)(m0 + row) * K + kt + col];
      *(uint4*)&Bs[row * 72 + col] = *(const uint4*)&B[(long)(n0 + row) * K + kt + col];
    }
    __syncthreads();
#pragma unroll
    for (int kk = 0; kk < 64; kk += 32) {
      bf16x8 a[4], b[4];
#pragma unroll
      for (int i = 0; i < 4; ++i)
        a[i] = *(const bf16x8*)&As[(wm + i * 16 + ln) * 72 + kk + quad * 8];
#pragma unroll
      for (int j = 0; j < 4; ++j)
        b[j] = *(const bf16x8*)&Bs[(wn + j * 16 + ln) * 72 + kk + quad * 8];
#pragma unroll
      for (int i = 0; i < 4; ++i)
#pragma unroll
        for (int j = 0; j < 4; ++j)
          acc[i][j] = MFMA16(a[i], b[j], acc[i][j]);
    }
    __syncthreads();
  }

  float dscale = 1.0f / (1.0f - 0.1f * (float)de_ptr[0]);

#pragma unroll
  for (int j = 0; j < 4; ++j) {
    int o = n0 + wn + j * 16 + ln;
    float bb = bias[o];
#pragma unroll
    for (int i = 0; i < 4; ++i) {
      int p = m0 + wm + i * 16 + quad * 4;
      long cidx = (long)o * M + p;
      f32x4 v = acc[i][j];
      float4 rx = *(const float4*)&xin[cidx];
      float4 st;
      st.x = rx.x + (v[0] + bb) * dscale;
      st.y = rx.y + (v[1] + bb) * dscale;
      st.z = rx.z + (v[2] + bb) * dscale;
      st.w = rx.w + (v[3] + bb) * dscale;
      *(float4*)&C[cidx] = st;
    }
  }
}

// ---------------------------------------------------------------------------
// Flash attention. grid (16 q-tiles, 128 (n,h)); 4 waves x 16 q-rows each.
// q_pd/k_pd: [(n*8+h)*1024 + p][64]; v_cp: [n][c'=h*64+d][1024 p]
// out y_pc: [n][1024 p][512 c']   (all bf16)
// ---------------------------------------------------------------------------
__global__ __launch_bounds__(256) void attn_kernel(
    const unsigned short* __restrict__ q_pd, const unsigned short* __restrict__ k_pd,
    const unsigned short* __restrict__ v_cp, unsigned short* __restrict__ y_pc)
{
  __shared__ unsigned short Ks[128 * 72];
  __shared__ unsigned short Vs[64 * 136];
  __shared__ unsigned short Ps[4 * 16 * 136];
  const int t = threadIdx.x, lane = t & 63, wv = t >> 6;
  const int quad = lane >> 4, ln = lane & 15;
  const int nh = blockIdx.y, n = nh >> 3, h = nh & 7;
  const int q0 = blockIdx.x * 64;

  bf16x8 qa[2];
  {
    const unsigned short* qb = q_pd + ((long)nh * 1024 + q0 + wv * 16 + ln) * 64;
    qa[0] = *(const bf16x8*)(qb + quad * 8);
    qa[1] = *(const bf16x8*)(qb + 32 + quad * 8);
  }

  f32x4 zero = {0.f, 0.f, 0.f, 0.f};
  float m_i[4], l_i[4];
  f32x4 o_acc[4];
#pragma unroll
  for (int r = 0; r < 4; ++r) { m_i[r] = -1e30f; l_i[r] = 0.f; }
#pragma unroll
  for (int nf = 0; nf < 4; ++nf) o_acc[nf] = zero;

  const unsigned short* kg0 = k_pd + (long)nh * 1024 * 64;
  const unsigned short* vg0 = v_cp + ((long)n * 512 + h * 64) * 1024;
  unsigned short* Pw = &Ps[wv * 16 * 136];

  for (int c = 0; c < 8; ++c) {
    const unsigned short* kg = kg0 + (long)c * 128 * 64;
    const unsigned short* vg = vg0 + c * 128;
#pragma unroll
    for (int i = 0; i < 4; ++i) {
      int chunk = t + 256 * i;
      int kr = chunk >> 3, kc = (chunk & 7) * 8;
      *(uint4*)&Ks[kr * 72 + kc] = *(const uint4*)(kg + kr * 64 + kc);
      int vr = chunk >> 4, vc = (chunk & 15) * 8;
      *(uint4*)&Vs[vr * 136 + vc] = *(const uint4*)(vg + (long)vr * 1024 + vc);
    }
    __syncthreads();

    f32x4 s[8];
#pragma unroll
    for (int j = 0; j < 8; ++j) s[j] = zero;
#pragma unroll
    for (int j = 0; j < 8; ++j) {
      bf16x8 b0 = *(const bf16x8*)&Ks[(j * 16 + ln) * 72 + quad * 8];
      s[j] = MFMA16(qa[0], b0, s[j]);
      bf16x8 b1 = *(const bf16x8*)&Ks[(j * 16 + ln) * 72 + 32 + quad * 8];
      s[j] = MFMA16(qa[1], b1, s[j]);
    }
#pragma unroll
    for (int j = 0; j < 8; ++j)
#pragma unroll
      for (int r = 0; r < 4; ++r) s[j][r] *= 0.125f;

#pragma unroll
    for (int r = 0; r < 4; ++r) {
      float mm = s[0][r];
#pragma unroll
      for (int j = 1; j < 8; ++j) mm = fmaxf(mm, s[j][r]);
#pragma unroll
      for (int off = 1; off < 16; off <<= 1) mm = fmaxf(mm, __shfl_xor(mm, off));
      float mnew = fmaxf(m_i[r], mm);
      float alpha = __expf(m_i[r] - mnew);
      m_i[r] = mnew;
      l_i[r] *= alpha;
#pragma unroll
      for (int nf = 0; nf < 4; ++nf) o_acc[nf][r] *= alpha;
      float ls = 0.f;
#pragma unroll
      for (int j = 0; j < 8; ++j) {
        float pv = __expf(s[j][r] - mnew);
        s[j][r] = pv;
        ls += pv;
      }
#pragma unroll
      for (int off = 1; off < 16; off <<= 1) ls += __shfl_xor(ls, off);
      l_i[r] += ls;
    }

#pragma unroll
    for (int j = 0; j < 8; ++j)
#pragma unroll
      for (int r = 0; r < 4; ++r)
        Pw[(quad * 4 + r) * 136 + j * 16 + ln] = f2bf(s[j][r]);
    __syncthreads();

#pragma unroll
    for (int nf = 0; nf < 4; ++nf)
#pragma unroll
      for (int k2 = 0; k2 < 4; ++k2) {
        bf16x8 ap = *(const bf16x8*)&Pw[ln * 136 + k2 * 32 + quad * 8];
        bf16x8 bv = *(const bf16x8*)&Vs[(nf * 16 + ln) * 136 + k2 * 32 + quad * 8];
        o_acc[nf] = MFMA16(ap, bv, o_acc[nf]);
      }
    __syncthreads();
  }

#pragma unroll
  for (int r = 0; r < 4; ++r) l_i[r] = 1.0f / l_i[r];
  const int p0 = q0 + wv * 16 + quad * 4;
  unsigned short* yb = y_pc + ((long)n * 1024 + p0) * 512 + h * 64;
#pragma unroll
  for (int nf = 0; nf < 4; ++nf) {
    int cc = nf * 16 + ln;
#pragma unroll
    for (int r = 0; r < 4; ++r)
      yb[(long)r * 512 + cc] = f2bf(o_acc[nf][r] * l_i[r]);
  }
}

// ---------------------------------------------------------------------------
extern "C" void kernel_launch(void* const* d_in, const int* in_sizes, int n_in,
                              void* d_out, int out_size, void* d_ws, size_t ws_size,
                              hipStream_t stream) {
  (void)in_sizes; (void)n_in; (void)out_size; (void)ws_size;
  const float* x     = (const float*)d_in[0];
  const float* qkv_w = (const float*)d_in[1];
  const float* qkv_b = (const float*)d_in[2];
  const float* out_w = (const float*)d_in[3];
  const float* out_b = (const float*)d_in[4];
  const int* de = (const int*)d_in[5];
  float* out = (float*)d_out;
  unsigned short* ws = (unsigned short*)d_ws;

  // ws layout (shorts), ~66 MiB total:
  //   [0, 8388608)            xT, reused as y_pc
  //   [8388608, 33554432)     qkv: q_pd | k_pd | v_cp (8388608 each)
  //   [33554432, 34340864)    wq bf16 (786432)
  //   [34340864, 34603008)    wo bf16 (262144)
  unsigned short* xT   = ws;
  unsigned short* qkv  = ws + 8388608;
  unsigned short* y_pc = ws;
  unsigned short* wq   = ws + 33554432;
  unsigned short* wo   = wq + 786432;

  cvt_bf16<<<3072, 256, 0, stream>>>(qkv_w, wq, 786432);
  cvt_bf16<<<1024, 256, 0, stream>>>(out_w, wo, 262144);

  transpose_cvt<<<dim3(32, 16, 16), 256, 0, stream>>>(x, xT);

  gemm_qkv<<<dim3(12, 8, 16), 256, 0, stream>>>(xT, wq, qkv, qkv_b);

  attn_kernel<<<dim3(16, 128), 256, 0, stream>>>(
      qkv, qkv + 8388608, qkv + 16777216, y_pc);

  gemm_out<<<dim3(4, 8, 16), 256, 0, stream>>>(
      y_pc, wo, out, out_b, x, de);
}